// Round 12
// baseline (1360.732 us; speedup 1.0000x reference)
//
#include <hip/hip_runtime.h>

// PhysicsRULModel fully-fused kernel for MI355X (gfx950).  R12 = R11 +
// serial-chain de-latency:
//  - wave 0: x-broadcast via v_readlane (uniform index) instead of __shfl
//    (dynamic __shfl lowers to ds_bpermute = LDS latency ON the recurrence
//    chain, 2x/step).
//  - wave 2: rolling prefetch of g1r[t+1] (interval-lagged, always valid)
//    so the b128 read latency is off the chain.
//  - epilogue positions rebalanced {2,6,2,6} over waves 4..7: waves 4/6
//    (sharing SIMD0/2 with serial waves 0/2, round-robin mapping) carry only
//    2 positions/stage -> less issue contention on the critical SIMDs.
//  - #pragma unroll 2 on serial loops for scheduling depth.
// Pipeline structure identical to R11 (barriers every 16 steps, 135 total):
//   wave 0: L0 (Whh0) self-recurrent -> h0r ring (f16)
//   wave 1: L1-ih (Wih1) on h0r (lag 1) -> g1r ring (f32 partials)
//   wave 2: L1-hh (Whh1) + combine, self-recurrent -> h1r ring (f16)
//   wave 3: physics MLP + health clamp-affine scan (lag 5)
//   waves 4-7: epilogue A (lag 3) / B (lag 4) / D (lag 6), resident f16 wts.

#define Bn 256
#define Tn 2048
#define NT 512
#define NI 134

typedef _Float16 h2 __attribute__((ext_vector_type(2)));
union HU { int i; h2 h; };

__device__ __forceinline__ h2 I2H(int v) { HU u; u.i = v; return u.h; }
__device__ __forceinline__ h2 F2H2(float a, float b) { h2 r; r.x = (_Float16)a; r.y = (_Float16)b; return r; }
__device__ __forceinline__ float rcpf_(float x) { return __builtin_amdgcn_rcpf(x); }
__device__ __forceinline__ float sigf_(float x) { return rcpf_(1.f + __expf(-x)); }
__device__ __forceinline__ float tanhf2_(float x) {
    float e = __expf(2.0f * x);
    return 1.0f - 2.0f * rcpf_(e + 1.0f);
}
__device__ __forceinline__ void dot2(float& acc, h2 w, h2 x) {
    asm("v_dot2_f32_f16 %0, %1, %2, %0" : "+v"(acc) : "v"(w), "v"(x));
}
__device__ __forceinline__ float rdlane_(float v, int l) {
    return __int_as_float(__builtin_amdgcn_readlane(__float_as_int(v), l));
}
#define DPPF(v, ctrl) __int_as_float(__builtin_amdgcn_update_dpp(0, __float_as_int(v), (ctrl), 0xF, 0xF, true))
#define LGKM0() asm volatile("s_waitcnt lgkmcnt(0)" ::: "memory")
#define UNP4(h, o, r) { h[(o)] = I2H((r).x); h[(o)+1] = I2H((r).y); h[(o)+2] = I2H((r).z); h[(o)+3] = I2H((r).w); }

__device__ __forceinline__ float wsum64_(float v) {
    v += DPPF(v, 0xB1); v += DPPF(v, 0x4E);
    v += __shfl_xor(v, 4); v += __shfl_xor(v, 8);
    v += __shfl_xor(v, 16); v += __shfl_xor(v, 32);
    return v;
}

__global__ __launch_bounds__(512, 1)
void fused_rul_kernel(
    const float* __restrict__ ts,   const float* __restrict__ sf,
    const float* __restrict__ Wih0, const float* __restrict__ Whh0,
    const float* __restrict__ bih0, const float* __restrict__ bhh0,
    const float* __restrict__ Wih1, const float* __restrict__ Whh1,
    const float* __restrict__ bih1, const float* __restrict__ bhh1,
    const float* __restrict__ seW1, const float* __restrict__ seb1,
    const float* __restrict__ seW2, const float* __restrict__ seb2,
    const float* __restrict__ pbW1, const float* __restrict__ pbb1,
    const float* __restrict__ pbW2, const float* __restrict__ pbb2,
    const float* __restrict__ pbW3, const float* __restrict__ pbb3,
    const float* __restrict__ drW1, const float* __restrict__ drb1,
    const float* __restrict__ drW2, const float* __restrict__ drb2,
    const float* __restrict__ drW3, const float* __restrict__ drb3,
    const float* __restrict__ ruW1, const float* __restrict__ rub1,
    const float* __restrict__ ruW2, const float* __restrict__ rub2,
    float* __restrict__ out)
{
    const int tid  = threadIdx.x;
    const int b    = blockIdx.x;
    const int lane = tid & 63;
    const int w    = tid >> 6;                        // wave 0..7

    // ---- LDS rings (~53 KB) ----
    __shared__ __align__(16) _Float16 h0r[64][64];    // h0(t), slot t&63
    __shared__ __align__(16) _Float16 h1r[64][64];    // h1(t), slot t&63
    __shared__ __align__(16) float4   g1r[32][64];    // L1 ih partials, slot t&31
    __shared__ __align__(16) _Float16 ssb[64][32];    // system_states, slot t&63
    __shared__ __align__(16) _Float16 se1b[4][32];    // wave-private
    __shared__ __align__(16) _Float16 dr1b[4][64];    // wave-private
    __shared__ float degb[32];                        // slot t&31
    __shared__ float hltb[32];                        // slot t&31
    __shared__ float phys_s[4];                       // [A, -Ea*1000/R, Ea, logA]

    const float* tsb = ts + (size_t)b * Tn * 2;
    float* outR = out + (size_t)b * Tn;
    float* outD = out + (size_t)Bn * Tn + (size_t)b * Tn;
    float* outH = out + 2 * (size_t)Bn * Tn + (size_t)b * Tn;

    if (w == 0) {
        // ================= wave 0: L0 recurrence =================
        h2 wf[128]; float b0[4], wx[4], wy[4];
        #pragma unroll
        for (int g = 0; g < 4; ++g) {
            const int row = (g << 6) + lane;
            const float* r = Whh0 + row * 64;
            #pragma unroll
            for (int k = 0; k < 32; ++k) wf[g * 32 + k] = F2H2(r[2 * k], r[2 * k + 1]);
            b0[g] = bih0[row] + bhh0[row];
            wx[g] = Wih0[row * 2]; wy[g] = Wih0[row * 2 + 1];
        }
        h2 hv[32];
        #pragma unroll
        for (int k = 0; k < 32; ++k) hv[k] = F2H2(0.f, 0.f);
        float c0 = 0.f;
        __syncthreads();
        for (int I = 0; I < NI; ++I) {
            const int base = I << 4;
            if (base < Tn) {
                float2 xp = make_float2(0.f, 0.f);
                if (lane < 16) xp = *(const float2*)(tsb + 2 * (base + lane));
                #pragma unroll 2
                for (int j = 0; j < 16; ++j) {
                    const int u = base + j;
                    float a0 = 0, a1 = 0, a2 = 0, a3 = 0, a4 = 0, a5 = 0, a6 = 0, a7 = 0;
                    #pragma unroll
                    for (int k = 0; k < 16; ++k) {
                        dot2(a0, wf[k],       hv[k]); dot2(a4, wf[16 + k],  hv[16 + k]);
                        dot2(a1, wf[32 + k],  hv[k]); dot2(a5, wf[48 + k],  hv[16 + k]);
                        dot2(a2, wf[64 + k],  hv[k]); dot2(a6, wf[80 + k],  hv[16 + k]);
                        dot2(a3, wf[96 + k],  hv[k]); dot2(a7, wf[112 + k], hv[16 + k]);
                    }
                    // uniform-index broadcast via v_readlane (no LDS on chain)
                    float sx = rdlane_(xp.x, j), sy = rdlane_(xp.y, j);
                    float pi = a0 + a4 + b0[0] + wx[0] * sx + wy[0] * sy;
                    float pf = a1 + a5 + b0[1] + wx[1] * sx + wy[1] * sy;
                    float pg = a2 + a6 + b0[2] + wx[2] * sx + wy[2] * sy;
                    float po = a3 + a7 + b0[3] + wx[3] * sx + wy[3] * sy;
                    float ai = sigf_(pi), af = sigf_(pf), ag = tanhf2_(pg), ao = sigf_(po);
                    c0 = fmaf(af, c0, ai * ag);
                    float h0n = ao * tanhf2_(c0);
                    h0r[u & 63][lane] = (_Float16)h0n;
                    LGKM0();
                    const int4* rp = (const int4*)&h0r[u & 63][0];
                    int4 r0 = rp[0], r1 = rp[1], r2 = rp[2], r3 = rp[3];
                    int4 r4 = rp[4], r5 = rp[5], r6 = rp[6], r7 = rp[7];
                    UNP4(hv, 0, r0);  UNP4(hv, 4, r1);  UNP4(hv, 8, r2);  UNP4(hv, 12, r3);
                    UNP4(hv, 16, r4); UNP4(hv, 20, r5); UNP4(hv, 24, r6); UNP4(hv, 28, r7);
                }
            }
            __syncthreads();
        }
    } else if (w == 1) {
        // ================= wave 1: L1 input-to-hidden =================
        h2 wf[128];
        #pragma unroll
        for (int g = 0; g < 4; ++g) {
            const float* r = Wih1 + ((g << 6) + lane) * 64;
            #pragma unroll
            for (int k = 0; k < 32; ++k) wf[g * 32 + k] = F2H2(r[2 * k], r[2 * k + 1]);
        }
        __syncthreads();
        for (int I = 0; I < NI; ++I) {
            const int tb = (I << 4) - 16;
            if (tb >= 0 && tb < Tn) {
                #pragma unroll 2
                for (int j = 0; j < 16; ++j) {
                    const int t = tb + j;
                    const int4* rp = (const int4*)&h0r[t & 63][0];
                    int4 r0 = rp[0], r1 = rp[1], r2 = rp[2], r3 = rp[3];
                    int4 r4 = rp[4], r5 = rp[5], r6 = rp[6], r7 = rp[7];
                    h2 hv[32];
                    UNP4(hv, 0, r0);  UNP4(hv, 4, r1);  UNP4(hv, 8, r2);  UNP4(hv, 12, r3);
                    UNP4(hv, 16, r4); UNP4(hv, 20, r5); UNP4(hv, 24, r6); UNP4(hv, 28, r7);
                    float a0 = 0, a1 = 0, a2 = 0, a3 = 0, a4 = 0, a5 = 0, a6 = 0, a7 = 0;
                    #pragma unroll
                    for (int k = 0; k < 16; ++k) {
                        dot2(a0, wf[k],       hv[k]); dot2(a4, wf[16 + k],  hv[16 + k]);
                        dot2(a1, wf[32 + k],  hv[k]); dot2(a5, wf[48 + k],  hv[16 + k]);
                        dot2(a2, wf[64 + k],  hv[k]); dot2(a6, wf[80 + k],  hv[16 + k]);
                        dot2(a3, wf[96 + k],  hv[k]); dot2(a7, wf[112 + k], hv[16 + k]);
                    }
                    g1r[t & 31][lane] = make_float4(a0 + a4, a1 + a5, a2 + a6, a3 + a7);
                }
            }
            __syncthreads();
        }
    } else if (w == 2) {
        // ================= wave 2: L1 hidden + combine =================
        h2 wf[128]; float b1[4];
        #pragma unroll
        for (int g = 0; g < 4; ++g) {
            const int row = (g << 6) + lane;
            const float* r = Whh1 + row * 64;
            #pragma unroll
            for (int k = 0; k < 32; ++k) wf[g * 32 + k] = F2H2(r[2 * k], r[2 * k + 1]);
            b1[g] = bih1[row] + bhh1[row];
        }
        h2 hv[32];
        #pragma unroll
        for (int k = 0; k < 32; ++k) hv[k] = F2H2(0.f, 0.f);
        float c1 = 0.f;
        __syncthreads();
        for (int I = 0; I < NI; ++I) {
            const int tb = (I << 4) - 32;
            if (tb >= 0 && tb < Tn) {
                // rolling prefetch: g1r window [tb, tb+15] fully written last interval
                float4 pcur = g1r[tb & 31][lane];
                #pragma unroll 2
                for (int j = 0; j < 16; ++j) {
                    const int t = tb + j;
                    float4 pnext = pcur;
                    if (j < 15) pnext = g1r[(t + 1) & 31][lane];
                    float a0 = 0, a1 = 0, a2 = 0, a3 = 0, a4 = 0, a5 = 0, a6 = 0, a7 = 0;
                    #pragma unroll
                    for (int k = 0; k < 16; ++k) {
                        dot2(a0, wf[k],       hv[k]); dot2(a4, wf[16 + k],  hv[16 + k]);
                        dot2(a1, wf[32 + k],  hv[k]); dot2(a5, wf[48 + k],  hv[16 + k]);
                        dot2(a2, wf[64 + k],  hv[k]); dot2(a6, wf[80 + k],  hv[16 + k]);
                        dot2(a3, wf[96 + k],  hv[k]); dot2(a7, wf[112 + k], hv[16 + k]);
                    }
                    float pi = pcur.x + a0 + a4 + b1[0];
                    float pf = pcur.y + a1 + a5 + b1[1];
                    float pg = pcur.z + a2 + a6 + b1[2];
                    float po = pcur.w + a3 + a7 + b1[3];
                    float ai = sigf_(pi), af = sigf_(pf), ag = tanhf2_(pg), ao = sigf_(po);
                    c1 = fmaf(af, c1, ai * ag);
                    float h1n = ao * tanhf2_(c1);
                    h1r[t & 63][lane] = (_Float16)h1n;
                    LGKM0();
                    const int4* rp = (const int4*)&h1r[t & 63][0];
                    int4 r0 = rp[0], r1 = rp[1], r2 = rp[2], r3 = rp[3];
                    int4 r4 = rp[4], r5 = rp[5], r6 = rp[6], r7 = rp[7];
                    UNP4(hv, 0, r0);  UNP4(hv, 4, r1);  UNP4(hv, 8, r2);  UNP4(hv, 12, r3);
                    UNP4(hv, 16, r4); UNP4(hv, 20, r5); UNP4(hv, 24, r6); UNP4(hv, 28, r7);
                    pcur = pnext;
                }
            }
            __syncthreads();
        }
    } else if (w == 3) {
        // ================= wave 3: physics + health scan =================
        if (lane == 0) {
            float p1[32];
            for (int o = 0; o < 32; ++o) {
                float a = pbb1[o];
                for (int k = 0; k < 3; ++k) a += pbW1[o * 3 + k] * sf[b * 3 + k];
                p1[o] = fmaxf(a, 0.f);
            }
            float p2[16];
            for (int o = 0; o < 16; ++o) {
                float a = pbb2[o];
                for (int k = 0; k < 32; ++k) a += pbW2[o * 32 + k] * p1[k];
                p2[o] = fmaxf(a, 0.f);
            }
            float Ea = pbb3[0], lA = pbb3[1];
            for (int k = 0; k < 16; ++k) { Ea += pbW3[k] * p2[k]; lA += pbW3[16 + k] * p2[k]; }
            phys_s[0] = __expf(lA);
            phys_s[1] = -Ea * 1000.0f / 8.314f;
            phys_s[2] = Ea;
            phys_s[3] = lA;
        }
        float hst = 1.0f;
        __syncthreads();
        for (int I = 0; I < NI; ++I) {
            const int t0s = (I << 4) - 80;
            if (t0s >= 0 && t0s < Tn) {
                const int t = lane;
                const float Af = phys_s[0], ne = phys_s[1];
                float a_ = 0.f, l_ = -1e30f, u_ = 1e30f;
                if (t < 16) {
                    float dg = degb[(t0s + t) & 31];
                    float tK = tsb[2 * (t0s + t)] + 273.15f;
                    float arr = Af * __expf(ne * rcpf_(tK));
                    a_ = -(0.7f * dg + 0.3f * arr);
                    l_ = 0.f; u_ = 1.f;
                }
                #pragma unroll
                for (int d = 1; d < 16; d <<= 1) {
                    float pa = __shfl_up(a_, d);
                    float pl = __shfl_up(l_, d);
                    float pu = __shfl_up(u_, d);
                    if (t >= d && t < 16) {
                        float na = pa + a_;
                        float nl = fminf(fmaxf(pl + a_, l_), u_);
                        float nu = fminf(fmaxf(pu + a_, l_), u_);
                        a_ = na; l_ = nl; u_ = nu;
                    }
                }
                float hval = fminf(fmaxf(hst + a_, l_), u_);
                if (t < 16) { hltb[(t0s + t) & 31] = hval; outH[t0s + t] = hval; }
                hst = __shfl(hval, 15);
            }
            __syncthreads();
        }
    } else {
        // ================= waves 4-7: epilogue stages A/B/D =================
        // position balance {2,6,2,6}: waves 4/6 (SIMD0/2, shared with serial
        // waves 0/2) carry 2 positions; waves 5/7 carry 6.
        const int ew = w - 4, jj = lane & 31, hh = lane >> 5;
        const int eoff = (ew == 0) ? 0 : (ew == 1) ? 2 : (ew == 2) ? 8 : 10;
        const int ecnt = (ew & 1) ? 6 : 2;
        h2 w1h[16], w2h[8], wd1h[16], wd2h[16], wr1h[8];
        float wt0, wt1, wt2, bb1, seb1r, seb2r, bb2, w3r, whc, brD, w2rD, drb3r, rub2r;
        {
            const float* r = seW1 + jj * 64 + hh * 32;
            #pragma unroll
            for (int k = 0; k < 16; ++k) w1h[k] = F2H2(r[2 * k], r[2 * k + 1]);
            r = seW2 + jj * 32 + hh * 16;
            #pragma unroll
            for (int k = 0; k < 8; ++k) w2h[k] = F2H2(r[2 * k], r[2 * k + 1]);
            r = drW1 + lane * 35;
            #pragma unroll
            for (int k = 0; k < 16; ++k) wd1h[k] = F2H2(r[2 * k], r[2 * k + 1]);
            wt0 = r[32]; wt1 = r[33]; wt2 = r[34];
            r = drW2 + jj * 64 + hh * 32;
            #pragma unroll
            for (int k = 0; k < 16; ++k) wd2h[k] = F2H2(r[2 * k], r[2 * k + 1]);
            r = ruW1 + jj * 33 + hh * 16;
            #pragma unroll
            for (int k = 0; k < 8; ++k) wr1h[k] = F2H2(r[2 * k], r[2 * k + 1]);
            seb1r = seb1[jj]; seb2r = seb2[jj];
            bb1 = drb1[lane]; bb2 = drb2[jj]; w3r = drW3[jj];
            whc = ruW1[jj * 33 + 32]; brD = rub1[jj]; w2rD = ruW2[jj];
            drb3r = drb3[0]; rub2r = rub2[0];
        }
        __syncthreads();
        for (int I = 0; I < NI; ++I) {
            const int Abase = (I << 4) - 48;
            const int Bbase = (I << 4) - 64;
            const int Dbase = (I << 4) - 96;
            // temp prefetch for stage B (hide VMEM latency behind stage A)
            float tpre[6];
            if (Bbase >= 0 && Bbase < Tn) {
                #pragma unroll
                for (int i = 0; i < 6; ++i)
                    if (i < ecnt) tpre[i] = tsb[2 * (Bbase + eoff + i)];
            }
            // ---- stage A: se1 + se2 ----
            if (Abase >= 0 && Abase < Tn) {
                #pragma unroll 1
                for (int i = 0; i < 6; ++i) {
                    if (i >= ecnt) break;
                    const int pos = Abase + eoff + i;
                    const int slot = pos & 63;
                    const int4* hp = (const int4*)(&h1r[slot][hh * 32]);
                    int4 q0 = hp[0], q1 = hp[1], q2 = hp[2], q3 = hp[3];
                    h2 hv16[16];
                    UNP4(hv16, 0, q0); UNP4(hv16, 4, q1); UNP4(hv16, 8, q2); UNP4(hv16, 12, q3);
                    float acc = 0.f;
                    #pragma unroll
                    for (int k = 0; k < 16; ++k) dot2(acc, w1h[k], hv16[k]);
                    acc += __shfl_xor(acc, 32);
                    float se1v = fmaxf(acc + seb1r, 0.f);
                    if (hh == 0) se1b[ew][jj] = (_Float16)se1v;
                    LGKM0();
                    const int4* sp = (const int4*)(&se1b[ew][hh * 16]);
                    int4 s0 = sp[0], s1 = sp[1];
                    h2 sv[8];
                    UNP4(sv, 0, s0); UNP4(sv, 4, s1);
                    float a2 = 0.f;
                    #pragma unroll
                    for (int k = 0; k < 8; ++k) dot2(a2, w2h[k], sv[k]);
                    a2 += __shfl_xor(a2, 32);
                    if (hh == 0) ssb[slot][jj] = (_Float16)(a2 + seb2r);
                }
            }
            // ---- stage B: dr1 + dr2 + dr3 ----
            if (Bbase >= 0 && Bbase < Tn) {
                const float ea_ = phys_s[2], la_ = phys_s[3];
                #pragma unroll 1
                for (int i = 0; i < 6; ++i) {
                    if (i >= ecnt) break;
                    const int pos = Bbase + eoff + i;
                    const int slot = pos & 63;
                    const int4* xp = (const int4*)(&ssb[slot][0]);
                    int4 x0 = xp[0], x1 = xp[1], x2 = xp[2], x3 = xp[3];
                    h2 xv[16];
                    UNP4(xv, 0, x0); UNP4(xv, 4, x1); UNP4(xv, 8, x2); UNP4(xv, 12, x3);
                    float acc = 0.f;
                    #pragma unroll
                    for (int k = 0; k < 16; ++k) dot2(acc, wd1h[k], xv[k]);
                    acc += wt0 * tpre[i] + wt1 * ea_ + wt2 * la_;
                    dr1b[ew][lane] = (_Float16)fmaxf(acc + bb1, 0.f);
                    LGKM0();
                    const int4* dp = (const int4*)(&dr1b[ew][hh * 32]);
                    int4 d0 = dp[0], d1 = dp[1], d2 = dp[2], d3 = dp[3];
                    h2 dv[16];
                    UNP4(dv, 0, d0); UNP4(dv, 4, d1); UNP4(dv, 8, d2); UNP4(dv, 12, d3);
                    float a2 = 0.f;
                    #pragma unroll
                    for (int k = 0; k < 16; ++k) dot2(a2, wd2h[k], dv[k]);
                    a2 += __shfl_xor(a2, 32);
                    float tt = w3r * fmaxf(a2 + bb2, 0.f);
                    float sum = wsum64_(tt);          // each jj counted twice
                    float deg = 0.5f * sum + drb3r;
                    if (lane == 0) { degb[pos & 31] = deg; outD[pos] = deg; }
                }
            }
            // ---- stage D: rul head ----
            if (Dbase >= 0 && Dbase < Tn) {
                #pragma unroll 1
                for (int i = 0; i < 6; ++i) {
                    if (i >= ecnt) break;
                    const int pos = Dbase + eoff + i;
                    const int slot = pos & 63;
                    const int4* xp = (const int4*)(&ssb[slot][hh * 16]);
                    int4 x0 = xp[0], x1 = xp[1];
                    h2 xv[8];
                    UNP4(xv, 0, x0); UNP4(xv, 4, x1);
                    float acc = 0.f;
                    #pragma unroll
                    for (int k = 0; k < 8; ++k) dot2(acc, wr1h[k], xv[k]);
                    acc += __shfl_xor(acc, 32);
                    float a = acc + brD + whc * hltb[pos & 31];
                    float pp = w2rD * fmaxf(a, 0.f);
                    float sum = wsum64_(pp);
                    if (lane == 0) outR[pos] = fmaxf(0.5f * sum + rub2r, 0.f);
                }
            }
            __syncthreads();
        }
    }
}

extern "C" void kernel_launch(void* const* d_in, const int* in_sizes, int n_in,
                              void* d_out, int out_size, void* d_ws, size_t ws_size,
                              hipStream_t stream) {
    const float* ts   = (const float*)d_in[0];
    const float* sf   = (const float*)d_in[1];
    const float* Wih0 = (const float*)d_in[2];
    const float* Whh0 = (const float*)d_in[3];
    const float* bih0 = (const float*)d_in[4];
    const float* bhh0 = (const float*)d_in[5];
    const float* Wih1 = (const float*)d_in[6];
    const float* Whh1 = (const float*)d_in[7];
    const float* bih1 = (const float*)d_in[8];
    const float* bhh1 = (const float*)d_in[9];
    const float* seW1 = (const float*)d_in[10];
    const float* seb1 = (const float*)d_in[11];
    const float* seW2 = (const float*)d_in[12];
    const float* seb2 = (const float*)d_in[13];
    const float* pbW1 = (const float*)d_in[14];
    const float* pbb1 = (const float*)d_in[15];
    const float* pbW2 = (const float*)d_in[16];
    const float* pbb2 = (const float*)d_in[17];
    const float* pbW3 = (const float*)d_in[18];
    const float* pbb3 = (const float*)d_in[19];
    const float* drW1 = (const float*)d_in[20];
    const float* drb1 = (const float*)d_in[21];
    const float* drW2 = (const float*)d_in[22];
    const float* drb2 = (const float*)d_in[23];
    const float* drW3 = (const float*)d_in[24];
    const float* drb3 = (const float*)d_in[25];
    const float* ruW1 = (const float*)d_in[26];
    const float* rub1 = (const float*)d_in[27];
    const float* ruW2 = (const float*)d_in[28];
    const float* rub2 = (const float*)d_in[29];
    float* out = (float*)d_out;

    fused_rul_kernel<<<dim3(Bn), dim3(NT), 0, stream>>>(
        ts, sf, Wih0, Whh0, bih0, bhh0, Wih1, Whh1, bih1, bhh1,
        seW1, seb1, seW2, seb2, pbW1, pbb1, pbW2, pbb2, pbW3, pbb3,
        drW1, drb1, drW2, drb2, drW3, drb3, ruW1, rub1, ruW2, rub2, out);
}

// Round 13
// 1163.345 us; speedup vs baseline: 1.1697x; 1.1697x over previous
//
#include <hip/hip_runtime.h>

// PhysicsRULModel fully-fused kernel for MI355X (gfx950).  R13.
// = R11 (best: 1145us) + three strictly-local serial-chain cuts:
//  - wave 0: x-broadcast via v_readlane (uniform index; dynamic __shfl
//    lowers to ds_bpermute = LDS latency on the recurrence chain).
//  - wave 2: rolling prefetch of g1r[t+1] (interval-lagged, always valid).
//  - waves 0/2: NO explicit lgkmcnt(0) between the h-row ds_write and the
//    readback ds_read_b128s -- per-wave DS ops are processed in order, so
//    read-after-write to the same row is safe; compiler still inserts the
//    waitcnt before first VALU use. Removes a full-drain from the chain.
// R12 regression (1361us) traced to bundling {2,6,2,6} epilogue rebalance
// (lengthened slowest wave's tail) + unroll 2 (schedule damage); both
// reverted: epilogue back to {4,4,4,4}, serial loops unroll 1.
// Pipeline (R11): barriers every 16 steps (135 total);
//   wave 0: L0 (Whh0) self-recurrent -> h0r (f16)
//   wave 1: L1-ih (Wih1) on h0r (lag 1) -> g1r (f32 partials)
//   wave 2: L1-hh (Whh1) + combine self-recurrent -> h1r (f16)
//   wave 3: physics MLP + health clamp-affine scan (lag 5)
//   waves 4-7: epilogue A (lag 3) / B (lag 4) / D (lag 6), resident f16 wts.

#define Bn 256
#define Tn 2048
#define NT 512
#define NI 134

typedef _Float16 h2 __attribute__((ext_vector_type(2)));
union HU { int i; h2 h; };

__device__ __forceinline__ h2 I2H(int v) { HU u; u.i = v; return u.h; }
__device__ __forceinline__ h2 F2H2(float a, float b) { h2 r; r.x = (_Float16)a; r.y = (_Float16)b; return r; }
__device__ __forceinline__ float rcpf_(float x) { return __builtin_amdgcn_rcpf(x); }
__device__ __forceinline__ float sigf_(float x) { return rcpf_(1.f + __expf(-x)); }
__device__ __forceinline__ float tanhf2_(float x) {
    float e = __expf(2.0f * x);
    return 1.0f - 2.0f * rcpf_(e + 1.0f);
}
__device__ __forceinline__ void dot2(float& acc, h2 w, h2 x) {
    asm("v_dot2_f32_f16 %0, %1, %2, %0" : "+v"(acc) : "v"(w), "v"(x));
}
__device__ __forceinline__ float rdlane_(float v, int l) {
    return __int_as_float(__builtin_amdgcn_readlane(__float_as_int(v), l));
}
#define DPPF(v, ctrl) __int_as_float(__builtin_amdgcn_update_dpp(0, __float_as_int(v), (ctrl), 0xF, 0xF, true))
#define LGKM0() asm volatile("s_waitcnt lgkmcnt(0)" ::: "memory")
#define UNP4(h, o, r) { h[(o)] = I2H((r).x); h[(o)+1] = I2H((r).y); h[(o)+2] = I2H((r).z); h[(o)+3] = I2H((r).w); }

__device__ __forceinline__ float wsum64_(float v) {
    v += DPPF(v, 0xB1); v += DPPF(v, 0x4E);
    v += __shfl_xor(v, 4); v += __shfl_xor(v, 8);
    v += __shfl_xor(v, 16); v += __shfl_xor(v, 32);
    return v;
}

__global__ __launch_bounds__(512, 1)
void fused_rul_kernel(
    const float* __restrict__ ts,   const float* __restrict__ sf,
    const float* __restrict__ Wih0, const float* __restrict__ Whh0,
    const float* __restrict__ bih0, const float* __restrict__ bhh0,
    const float* __restrict__ Wih1, const float* __restrict__ Whh1,
    const float* __restrict__ bih1, const float* __restrict__ bhh1,
    const float* __restrict__ seW1, const float* __restrict__ seb1,
    const float* __restrict__ seW2, const float* __restrict__ seb2,
    const float* __restrict__ pbW1, const float* __restrict__ pbb1,
    const float* __restrict__ pbW2, const float* __restrict__ pbb2,
    const float* __restrict__ pbW3, const float* __restrict__ pbb3,
    const float* __restrict__ drW1, const float* __restrict__ drb1,
    const float* __restrict__ drW2, const float* __restrict__ drb2,
    const float* __restrict__ drW3, const float* __restrict__ drb3,
    const float* __restrict__ ruW1, const float* __restrict__ rub1,
    const float* __restrict__ ruW2, const float* __restrict__ rub2,
    float* __restrict__ out)
{
    const int tid  = threadIdx.x;
    const int b    = blockIdx.x;
    const int lane = tid & 63;
    const int w    = tid >> 6;                        // wave 0..7

    // ---- LDS rings (~53 KB) ----
    __shared__ __align__(16) _Float16 h0r[64][64];    // h0(t), slot t&63
    __shared__ __align__(16) _Float16 h1r[64][64];    // h1(t), slot t&63
    __shared__ __align__(16) float4   g1r[32][64];    // L1 ih partials, slot t&31
    __shared__ __align__(16) _Float16 ssb[64][32];    // system_states, slot t&63
    __shared__ __align__(16) _Float16 se1b[4][32];    // wave-private
    __shared__ __align__(16) _Float16 dr1b[4][64];    // wave-private
    __shared__ float degb[32];                        // slot t&31
    __shared__ float hltb[32];                        // slot t&31
    __shared__ float phys_s[4];                       // [A, -Ea*1000/R, Ea, logA]

    const float* tsb = ts + (size_t)b * Tn * 2;
    float* outR = out + (size_t)b * Tn;
    float* outD = out + (size_t)Bn * Tn + (size_t)b * Tn;
    float* outH = out + 2 * (size_t)Bn * Tn + (size_t)b * Tn;

    if (w == 0) {
        // ================= wave 0: L0 recurrence =================
        h2 wf[128]; float b0[4], wx[4], wy[4];
        #pragma unroll
        for (int g = 0; g < 4; ++g) {
            const int row = (g << 6) + lane;
            const float* r = Whh0 + row * 64;
            #pragma unroll
            for (int k = 0; k < 32; ++k) wf[g * 32 + k] = F2H2(r[2 * k], r[2 * k + 1]);
            b0[g] = bih0[row] + bhh0[row];
            wx[g] = Wih0[row * 2]; wy[g] = Wih0[row * 2 + 1];
        }
        h2 hv[32];
        #pragma unroll
        for (int k = 0; k < 32; ++k) hv[k] = F2H2(0.f, 0.f);
        float c0 = 0.f;
        __syncthreads();
        for (int I = 0; I < NI; ++I) {
            const int base = I << 4;
            if (base < Tn) {
                float2 xp = make_float2(0.f, 0.f);
                if (lane < 16) xp = *(const float2*)(tsb + 2 * (base + lane));
                #pragma unroll 1
                for (int j = 0; j < 16; ++j) {
                    const int u = base + j;
                    float a0 = 0, a1 = 0, a2 = 0, a3 = 0, a4 = 0, a5 = 0, a6 = 0, a7 = 0;
                    #pragma unroll
                    for (int k = 0; k < 16; ++k) {
                        dot2(a0, wf[k],       hv[k]); dot2(a4, wf[16 + k],  hv[16 + k]);
                        dot2(a1, wf[32 + k],  hv[k]); dot2(a5, wf[48 + k],  hv[16 + k]);
                        dot2(a2, wf[64 + k],  hv[k]); dot2(a6, wf[80 + k],  hv[16 + k]);
                        dot2(a3, wf[96 + k],  hv[k]); dot2(a7, wf[112 + k], hv[16 + k]);
                    }
                    // uniform-index broadcast via v_readlane (no LDS on chain)
                    float sx = rdlane_(xp.x, j), sy = rdlane_(xp.y, j);
                    float pi = a0 + a4 + b0[0] + wx[0] * sx + wy[0] * sy;
                    float pf = a1 + a5 + b0[1] + wx[1] * sx + wy[1] * sy;
                    float pg = a2 + a6 + b0[2] + wx[2] * sx + wy[2] * sy;
                    float po = a3 + a7 + b0[3] + wx[3] * sx + wy[3] * sy;
                    float ai = sigf_(pi), af = sigf_(pf), ag = tanhf2_(pg), ao = sigf_(po);
                    c0 = fmaf(af, c0, ai * ag);
                    float h0n = ao * tanhf2_(c0);
                    h0r[u & 63][lane] = (_Float16)h0n;
                    // no explicit lgkmcnt(0): per-wave DS ops process in
                    // order, so the readback below sees this write; the
                    // compiler inserts the waitcnt before first VALU use.
                    const int4* rp = (const int4*)&h0r[u & 63][0];
                    int4 r0 = rp[0], r1 = rp[1], r2 = rp[2], r3 = rp[3];
                    int4 r4 = rp[4], r5 = rp[5], r6 = rp[6], r7 = rp[7];
                    UNP4(hv, 0, r0);  UNP4(hv, 4, r1);  UNP4(hv, 8, r2);  UNP4(hv, 12, r3);
                    UNP4(hv, 16, r4); UNP4(hv, 20, r5); UNP4(hv, 24, r6); UNP4(hv, 28, r7);
                }
            }
            __syncthreads();
        }
    } else if (w == 1) {
        // ================= wave 1: L1 input-to-hidden =================
        h2 wf[128];
        #pragma unroll
        for (int g = 0; g < 4; ++g) {
            const float* r = Wih1 + ((g << 6) + lane) * 64;
            #pragma unroll
            for (int k = 0; k < 32; ++k) wf[g * 32 + k] = F2H2(r[2 * k], r[2 * k + 1]);
        }
        __syncthreads();
        for (int I = 0; I < NI; ++I) {
            const int tb = (I << 4) - 16;
            if (tb >= 0 && tb < Tn) {
                #pragma unroll 1
                for (int j = 0; j < 16; ++j) {
                    const int t = tb + j;
                    const int4* rp = (const int4*)&h0r[t & 63][0];
                    int4 r0 = rp[0], r1 = rp[1], r2 = rp[2], r3 = rp[3];
                    int4 r4 = rp[4], r5 = rp[5], r6 = rp[6], r7 = rp[7];
                    h2 hv[32];
                    UNP4(hv, 0, r0);  UNP4(hv, 4, r1);  UNP4(hv, 8, r2);  UNP4(hv, 12, r3);
                    UNP4(hv, 16, r4); UNP4(hv, 20, r5); UNP4(hv, 24, r6); UNP4(hv, 28, r7);
                    float a0 = 0, a1 = 0, a2 = 0, a3 = 0, a4 = 0, a5 = 0, a6 = 0, a7 = 0;
                    #pragma unroll
                    for (int k = 0; k < 16; ++k) {
                        dot2(a0, wf[k],       hv[k]); dot2(a4, wf[16 + k],  hv[16 + k]);
                        dot2(a1, wf[32 + k],  hv[k]); dot2(a5, wf[48 + k],  hv[16 + k]);
                        dot2(a2, wf[64 + k],  hv[k]); dot2(a6, wf[80 + k],  hv[16 + k]);
                        dot2(a3, wf[96 + k],  hv[k]); dot2(a7, wf[112 + k], hv[16 + k]);
                    }
                    g1r[t & 31][lane] = make_float4(a0 + a4, a1 + a5, a2 + a6, a3 + a7);
                }
            }
            __syncthreads();
        }
    } else if (w == 2) {
        // ================= wave 2: L1 hidden + combine =================
        h2 wf[128]; float b1[4];
        #pragma unroll
        for (int g = 0; g < 4; ++g) {
            const int row = (g << 6) + lane;
            const float* r = Whh1 + row * 64;
            #pragma unroll
            for (int k = 0; k < 32; ++k) wf[g * 32 + k] = F2H2(r[2 * k], r[2 * k + 1]);
            b1[g] = bih1[row] + bhh1[row];
        }
        h2 hv[32];
        #pragma unroll
        for (int k = 0; k < 32; ++k) hv[k] = F2H2(0.f, 0.f);
        float c1 = 0.f;
        __syncthreads();
        for (int I = 0; I < NI; ++I) {
            const int tb = (I << 4) - 32;
            if (tb >= 0 && tb < Tn) {
                // rolling prefetch: g1r window [tb, tb+15] fully written last interval
                float4 pcur = g1r[tb & 31][lane];
                #pragma unroll 1
                for (int j = 0; j < 16; ++j) {
                    const int t = tb + j;
                    float4 pnext = pcur;
                    if (j < 15) pnext = g1r[(t + 1) & 31][lane];
                    float a0 = 0, a1 = 0, a2 = 0, a3 = 0, a4 = 0, a5 = 0, a6 = 0, a7 = 0;
                    #pragma unroll
                    for (int k = 0; k < 16; ++k) {
                        dot2(a0, wf[k],       hv[k]); dot2(a4, wf[16 + k],  hv[16 + k]);
                        dot2(a1, wf[32 + k],  hv[k]); dot2(a5, wf[48 + k],  hv[16 + k]);
                        dot2(a2, wf[64 + k],  hv[k]); dot2(a6, wf[80 + k],  hv[16 + k]);
                        dot2(a3, wf[96 + k],  hv[k]); dot2(a7, wf[112 + k], hv[16 + k]);
                    }
                    float pi = pcur.x + a0 + a4 + b1[0];
                    float pf = pcur.y + a1 + a5 + b1[1];
                    float pg = pcur.z + a2 + a6 + b1[2];
                    float po = pcur.w + a3 + a7 + b1[3];
                    float ai = sigf_(pi), af = sigf_(pf), ag = tanhf2_(pg), ao = sigf_(po);
                    c1 = fmaf(af, c1, ai * ag);
                    float h1n = ao * tanhf2_(c1);
                    h1r[t & 63][lane] = (_Float16)h1n;
                    // no explicit lgkmcnt(0): per-wave DS in-order (see wave 0)
                    const int4* rp = (const int4*)&h1r[t & 63][0];
                    int4 r0 = rp[0], r1 = rp[1], r2 = rp[2], r3 = rp[3];
                    int4 r4 = rp[4], r5 = rp[5], r6 = rp[6], r7 = rp[7];
                    UNP4(hv, 0, r0);  UNP4(hv, 4, r1);  UNP4(hv, 8, r2);  UNP4(hv, 12, r3);
                    UNP4(hv, 16, r4); UNP4(hv, 20, r5); UNP4(hv, 24, r6); UNP4(hv, 28, r7);
                    pcur = pnext;
                }
            }
            __syncthreads();
        }
    } else if (w == 3) {
        // ================= wave 3: physics + health scan =================
        if (lane == 0) {
            float p1[32];
            for (int o = 0; o < 32; ++o) {
                float a = pbb1[o];
                for (int k = 0; k < 3; ++k) a += pbW1[o * 3 + k] * sf[b * 3 + k];
                p1[o] = fmaxf(a, 0.f);
            }
            float p2[16];
            for (int o = 0; o < 16; ++o) {
                float a = pbb2[o];
                for (int k = 0; k < 32; ++k) a += pbW2[o * 32 + k] * p1[k];
                p2[o] = fmaxf(a, 0.f);
            }
            float Ea = pbb3[0], lA = pbb3[1];
            for (int k = 0; k < 16; ++k) { Ea += pbW3[k] * p2[k]; lA += pbW3[16 + k] * p2[k]; }
            phys_s[0] = __expf(lA);
            phys_s[1] = -Ea * 1000.0f / 8.314f;
            phys_s[2] = Ea;
            phys_s[3] = lA;
        }
        float hst = 1.0f;
        __syncthreads();
        for (int I = 0; I < NI; ++I) {
            const int t0s = (I << 4) - 80;
            if (t0s >= 0 && t0s < Tn) {
                const int t = lane;
                const float Af = phys_s[0], ne = phys_s[1];
                float a_ = 0.f, l_ = -1e30f, u_ = 1e30f;
                if (t < 16) {
                    float dg = degb[(t0s + t) & 31];
                    float tK = tsb[2 * (t0s + t)] + 273.15f;
                    float arr = Af * __expf(ne * rcpf_(tK));
                    a_ = -(0.7f * dg + 0.3f * arr);
                    l_ = 0.f; u_ = 1.f;
                }
                #pragma unroll
                for (int d = 1; d < 16; d <<= 1) {
                    float pa = __shfl_up(a_, d);
                    float pl = __shfl_up(l_, d);
                    float pu = __shfl_up(u_, d);
                    if (t >= d && t < 16) {
                        float na = pa + a_;
                        float nl = fminf(fmaxf(pl + a_, l_), u_);
                        float nu = fminf(fmaxf(pu + a_, l_), u_);
                        a_ = na; l_ = nl; u_ = nu;
                    }
                }
                float hval = fminf(fmaxf(hst + a_, l_), u_);
                if (t < 16) { hltb[(t0s + t) & 31] = hval; outH[t0s + t] = hval; }
                hst = __shfl(hval, 15);
            }
            __syncthreads();
        }
    } else {
        // ================= waves 4-7: epilogue stages A/B/D =================
        const int ew = w - 4, jj = lane & 31, hh = lane >> 5;
        h2 w1h[16], w2h[8], wd1h[16], wd2h[16], wr1h[8];
        float wt0, wt1, wt2, bb1, seb1r, seb2r, bb2, w3r, whc, brD, w2rD, drb3r, rub2r;
        {
            const float* r = seW1 + jj * 64 + hh * 32;
            #pragma unroll
            for (int k = 0; k < 16; ++k) w1h[k] = F2H2(r[2 * k], r[2 * k + 1]);
            r = seW2 + jj * 32 + hh * 16;
            #pragma unroll
            for (int k = 0; k < 8; ++k) w2h[k] = F2H2(r[2 * k], r[2 * k + 1]);
            r = drW1 + lane * 35;
            #pragma unroll
            for (int k = 0; k < 16; ++k) wd1h[k] = F2H2(r[2 * k], r[2 * k + 1]);
            wt0 = r[32]; wt1 = r[33]; wt2 = r[34];
            r = drW2 + jj * 64 + hh * 32;
            #pragma unroll
            for (int k = 0; k < 16; ++k) wd2h[k] = F2H2(r[2 * k], r[2 * k + 1]);
            r = ruW1 + jj * 33 + hh * 16;
            #pragma unroll
            for (int k = 0; k < 8; ++k) wr1h[k] = F2H2(r[2 * k], r[2 * k + 1]);
            seb1r = seb1[jj]; seb2r = seb2[jj];
            bb1 = drb1[lane]; bb2 = drb2[jj]; w3r = drW3[jj];
            whc = ruW1[jj * 33 + 32]; brD = rub1[jj]; w2rD = ruW2[jj];
            drb3r = drb3[0]; rub2r = rub2[0];
        }
        __syncthreads();
        for (int I = 0; I < NI; ++I) {
            const int Abase = (I << 4) - 48;
            const int Bbase = (I << 4) - 64;
            const int Dbase = (I << 4) - 96;
            // temp prefetch for stage B (hide VMEM latency behind stage A)
            float tpre[4];
            if (Bbase >= 0 && Bbase < Tn) {
                #pragma unroll
                for (int i = 0; i < 4; ++i) tpre[i] = tsb[2 * (Bbase + (ew << 2) + i)];
            }
            // ---- stage A: se1 + se2 for [Abase, Abase+16) ----
            if (Abase >= 0 && Abase < Tn) {
                #pragma unroll 1
                for (int i = 0; i < 4; ++i) {
                    const int pos = Abase + (ew << 2) + i;
                    const int slot = pos & 63;
                    const int4* hp = (const int4*)(&h1r[slot][hh * 32]);
                    int4 q0 = hp[0], q1 = hp[1], q2 = hp[2], q3 = hp[3];
                    h2 hv16[16];
                    UNP4(hv16, 0, q0); UNP4(hv16, 4, q1); UNP4(hv16, 8, q2); UNP4(hv16, 12, q3);
                    float acc = 0.f;
                    #pragma unroll
                    for (int k = 0; k < 16; ++k) dot2(acc, w1h[k], hv16[k]);
                    acc += __shfl_xor(acc, 32);
                    float se1v = fmaxf(acc + seb1r, 0.f);
                    if (hh == 0) se1b[ew][jj] = (_Float16)se1v;
                    LGKM0();
                    const int4* sp = (const int4*)(&se1b[ew][hh * 16]);
                    int4 s0 = sp[0], s1 = sp[1];
                    h2 sv[8];
                    UNP4(sv, 0, s0); UNP4(sv, 4, s1);
                    float a2 = 0.f;
                    #pragma unroll
                    for (int k = 0; k < 8; ++k) dot2(a2, w2h[k], sv[k]);
                    a2 += __shfl_xor(a2, 32);
                    if (hh == 0) ssb[slot][jj] = (_Float16)(a2 + seb2r);
                }
            }
            // ---- stage B: dr1 + dr2 + dr3 for [Bbase, Bbase+16) ----
            if (Bbase >= 0 && Bbase < Tn) {
                const float ea_ = phys_s[2], la_ = phys_s[3];
                #pragma unroll 1
                for (int i = 0; i < 4; ++i) {
                    const int pos = Bbase + (ew << 2) + i;
                    const int slot = pos & 63;
                    const int4* xp = (const int4*)(&ssb[slot][0]);
                    int4 x0 = xp[0], x1 = xp[1], x2 = xp[2], x3 = xp[3];
                    h2 xv[16];
                    UNP4(xv, 0, x0); UNP4(xv, 4, x1); UNP4(xv, 8, x2); UNP4(xv, 12, x3);
                    float acc = 0.f;
                    #pragma unroll
                    for (int k = 0; k < 16; ++k) dot2(acc, wd1h[k], xv[k]);
                    acc += wt0 * tpre[i] + wt1 * ea_ + wt2 * la_;
                    dr1b[ew][lane] = (_Float16)fmaxf(acc + bb1, 0.f);
                    LGKM0();
                    const int4* dp = (const int4*)(&dr1b[ew][hh * 32]);
                    int4 d0 = dp[0], d1 = dp[1], d2 = dp[2], d3 = dp[3];
                    h2 dv[16];
                    UNP4(dv, 0, d0); UNP4(dv, 4, d1); UNP4(dv, 8, d2); UNP4(dv, 12, d3);
                    float a2 = 0.f;
                    #pragma unroll
                    for (int k = 0; k < 16; ++k) dot2(a2, wd2h[k], dv[k]);
                    a2 += __shfl_xor(a2, 32);
                    float tt = w3r * fmaxf(a2 + bb2, 0.f);
                    float sum = wsum64_(tt);          // each jj counted twice
                    float deg = 0.5f * sum + drb3r;
                    if (lane == 0) { degb[pos & 31] = deg; outD[pos] = deg; }
                }
            }
            // ---- stage D: rul head for [Dbase, Dbase+16) ----
            if (Dbase >= 0 && Dbase < Tn) {
                #pragma unroll 1
                for (int i = 0; i < 4; ++i) {
                    const int pos = Dbase + (ew << 2) + i;
                    const int slot = pos & 63;
                    const int4* xp = (const int4*)(&ssb[slot][hh * 16]);
                    int4 x0 = xp[0], x1 = xp[1];
                    h2 xv[8];
                    UNP4(xv, 0, x0); UNP4(xv, 4, x1);
                    float acc = 0.f;
                    #pragma unroll
                    for (int k = 0; k < 8; ++k) dot2(acc, wr1h[k], xv[k]);
                    acc += __shfl_xor(acc, 32);
                    float a = acc + brD + whc * hltb[pos & 31];
                    float pp = w2rD * fmaxf(a, 0.f);
                    float sum = wsum64_(pp);
                    if (lane == 0) outR[pos] = fmaxf(0.5f * sum + rub2r, 0.f);
                }
            }
            __syncthreads();
        }
    }
}

extern "C" void kernel_launch(void* const* d_in, const int* in_sizes, int n_in,
                              void* d_out, int out_size, void* d_ws, size_t ws_size,
                              hipStream_t stream) {
    const float* ts   = (const float*)d_in[0];
    const float* sf   = (const float*)d_in[1];
    const float* Wih0 = (const float*)d_in[2];
    const float* Whh0 = (const float*)d_in[3];
    const float* bih0 = (const float*)d_in[4];
    const float* bhh0 = (const float*)d_in[5];
    const float* Wih1 = (const float*)d_in[6];
    const float* Whh1 = (const float*)d_in[7];
    const float* bih1 = (const float*)d_in[8];
    const float* bhh1 = (const float*)d_in[9];
    const float* seW1 = (const float*)d_in[10];
    const float* seb1 = (const float*)d_in[11];
    const float* seW2 = (const float*)d_in[12];
    const float* seb2 = (const float*)d_in[13];
    const float* pbW1 = (const float*)d_in[14];
    const float* pbb1 = (const float*)d_in[15];
    const float* pbW2 = (const float*)d_in[16];
    const float* pbb2 = (const float*)d_in[17];
    const float* pbW3 = (const float*)d_in[18];
    const float* pbb3 = (const float*)d_in[19];
    const float* drW1 = (const float*)d_in[20];
    const float* drb1 = (const float*)d_in[21];
    const float* drW2 = (const float*)d_in[22];
    const float* drb2 = (const float*)d_in[23];
    const float* drW3 = (const float*)d_in[24];
    const float* drb3 = (const float*)d_in[25];
    const float* ruW1 = (const float*)d_in[26];
    const float* rub1 = (const float*)d_in[27];
    const float* ruW2 = (const float*)d_in[28];
    const float* rub2 = (const float*)d_in[29];
    float* out = (float*)d_out;

    fused_rul_kernel<<<dim3(Bn), dim3(NT), 0, stream>>>(
        ts, sf, Wih0, Whh0, bih0, bhh0, Wih1, Whh1, bih1, bhh1,
        seW1, seb1, seW2, seb2, pbW1, pbb1, pbW2, pbb2, pbW3, pbb3,
        drW1, drb1, drW2, drb2, drW3, drb3, ruW1, rub1, ruW2, rub2, out);
}

// Round 14
// 1058.388 us; speedup vs baseline: 1.2857x; 1.0992x over previous
//
#include <hip/hip_runtime.h>

// PhysicsRULModel fully-fused kernel for MI355X (gfx950).  R14.
// = R13 (1163us ~ R11 1145us) + ONE theme: critical-SIMD decongestion.
//  - wave renumbering (SIMD = wave&3): w0=L0 + w4=health share SIMD0
//    (health is nearly idle -> L0 gets the SIMD to itself); w1=L1ih+w5=epi;
//    w2=L1hh+w6=epi; w3=epi+w7=epi. Previously serial waves 0/2 shared
//    SIMDs with full epilogue waves.
//  - wsum64 -> DPP row_shr 1/2/4/8 + row_bcast15/31 chain (pure VALU; sum
//    in lane 63, fetched via v_readlane). Removes 4 ds_swizzle per call
//    (~8 DS ops/step) from the shared LDS pipe.
// Pipeline unchanged (R11): barriers every 16 steps (135 total);
//   L0 (Whh0) self-recurrent -> h0r (f16); L1-ih (Wih1) on h0r (lag 1)
//   -> g1r (f32); L1-hh (Whh1)+combine self-recurrent -> h1r (f16);
//   health clamp-affine scan (lag 5); epilogue A (lag 3)/B (lag 4)/D (lag 6)
//   with resident f16 weights. readlane x-broadcast + g1r rolling prefetch
//   + no explicit lgkm drain on serial readbacks (R13, verified).

#define Bn 256
#define Tn 2048
#define NT 512
#define NI 134

typedef _Float16 h2 __attribute__((ext_vector_type(2)));
union HU { int i; h2 h; };

__device__ __forceinline__ h2 I2H(int v) { HU u; u.i = v; return u.h; }
__device__ __forceinline__ h2 F2H2(float a, float b) { h2 r; r.x = (_Float16)a; r.y = (_Float16)b; return r; }
__device__ __forceinline__ float rcpf_(float x) { return __builtin_amdgcn_rcpf(x); }
__device__ __forceinline__ float sigf_(float x) { return rcpf_(1.f + __expf(-x)); }
__device__ __forceinline__ float tanhf2_(float x) {
    float e = __expf(2.0f * x);
    return 1.0f - 2.0f * rcpf_(e + 1.0f);
}
__device__ __forceinline__ void dot2(float& acc, h2 w, h2 x) {
    asm("v_dot2_f32_f16 %0, %1, %2, %0" : "+v"(acc) : "v"(w), "v"(x));
}
__device__ __forceinline__ float rdlane_(float v, int l) {
    return __int_as_float(__builtin_amdgcn_readlane(__float_as_int(v), l));
}
#define DPPF(v, ctrl) __int_as_float(__builtin_amdgcn_update_dpp(0, __float_as_int(v), (ctrl), 0xF, 0xF, true))
#define LGKM0() asm volatile("s_waitcnt lgkmcnt(0)" ::: "memory")
#define UNP4(h, o, r) { h[(o)] = I2H((r).x); h[(o)+1] = I2H((r).y); h[(o)+2] = I2H((r).z); h[(o)+3] = I2H((r).w); }

// full-wave sum via DPP only (no LDS pipe); result valid in lane 63.
__device__ __forceinline__ float wsum64_dpp_(float v) {
    v += DPPF(v, 0x111);   // row_shr:1
    v += DPPF(v, 0x112);   // row_shr:2
    v += DPPF(v, 0x114);   // row_shr:4
    v += DPPF(v, 0x118);   // row_shr:8  -> lane 15/31/47/63 hold row sums
    v += DPPF(v, 0x142);   // row_bcast15 -> lane31 = r0+r1, lane63 = r2+r3
    v += DPPF(v, 0x143);   // row_bcast31 -> lane63 = total
    return v;
}

__global__ __launch_bounds__(512, 1)
void fused_rul_kernel(
    const float* __restrict__ ts,   const float* __restrict__ sf,
    const float* __restrict__ Wih0, const float* __restrict__ Whh0,
    const float* __restrict__ bih0, const float* __restrict__ bhh0,
    const float* __restrict__ Wih1, const float* __restrict__ Whh1,
    const float* __restrict__ bih1, const float* __restrict__ bhh1,
    const float* __restrict__ seW1, const float* __restrict__ seb1,
    const float* __restrict__ seW2, const float* __restrict__ seb2,
    const float* __restrict__ pbW1, const float* __restrict__ pbb1,
    const float* __restrict__ pbW2, const float* __restrict__ pbb2,
    const float* __restrict__ pbW3, const float* __restrict__ pbb3,
    const float* __restrict__ drW1, const float* __restrict__ drb1,
    const float* __restrict__ drW2, const float* __restrict__ drb2,
    const float* __restrict__ drW3, const float* __restrict__ drb3,
    const float* __restrict__ ruW1, const float* __restrict__ rub1,
    const float* __restrict__ ruW2, const float* __restrict__ rub2,
    float* __restrict__ out)
{
    const int tid  = threadIdx.x;
    const int b    = blockIdx.x;
    const int lane = tid & 63;
    const int w    = tid >> 6;                        // wave 0..7

    // ---- LDS rings (~53 KB) ----
    __shared__ __align__(16) _Float16 h0r[64][64];    // h0(t), slot t&63
    __shared__ __align__(16) _Float16 h1r[64][64];    // h1(t), slot t&63
    __shared__ __align__(16) float4   g1r[32][64];    // L1 ih partials, slot t&31
    __shared__ __align__(16) _Float16 ssb[64][32];    // system_states, slot t&63
    __shared__ __align__(16) _Float16 se1b[4][32];    // epilogue-wave-private
    __shared__ __align__(16) _Float16 dr1b[4][64];    // epilogue-wave-private
    __shared__ float degb[32];                        // slot t&31
    __shared__ float hltb[32];                        // slot t&31
    __shared__ float phys_s[4];                       // [A, -Ea*1000/R, Ea, logA]

    const float* tsb = ts + (size_t)b * Tn * 2;
    float* outR = out + (size_t)b * Tn;
    float* outD = out + (size_t)Bn * Tn + (size_t)b * Tn;
    float* outH = out + 2 * (size_t)Bn * Tn + (size_t)b * Tn;

    if (w == 0) {
        // ================= wave 0 (SIMD0): L0 recurrence =================
        h2 wf[128]; float b0[4], wx[4], wy[4];
        #pragma unroll
        for (int g = 0; g < 4; ++g) {
            const int row = (g << 6) + lane;
            const float* r = Whh0 + row * 64;
            #pragma unroll
            for (int k = 0; k < 32; ++k) wf[g * 32 + k] = F2H2(r[2 * k], r[2 * k + 1]);
            b0[g] = bih0[row] + bhh0[row];
            wx[g] = Wih0[row * 2]; wy[g] = Wih0[row * 2 + 1];
        }
        h2 hv[32];
        #pragma unroll
        for (int k = 0; k < 32; ++k) hv[k] = F2H2(0.f, 0.f);
        float c0 = 0.f;
        __syncthreads();
        for (int I = 0; I < NI; ++I) {
            const int base = I << 4;
            if (base < Tn) {
                float2 xp = make_float2(0.f, 0.f);
                if (lane < 16) xp = *(const float2*)(tsb + 2 * (base + lane));
                #pragma unroll 1
                for (int j = 0; j < 16; ++j) {
                    const int u = base + j;
                    float a0 = 0, a1 = 0, a2 = 0, a3 = 0, a4 = 0, a5 = 0, a6 = 0, a7 = 0;
                    #pragma unroll
                    for (int k = 0; k < 16; ++k) {
                        dot2(a0, wf[k],       hv[k]); dot2(a4, wf[16 + k],  hv[16 + k]);
                        dot2(a1, wf[32 + k],  hv[k]); dot2(a5, wf[48 + k],  hv[16 + k]);
                        dot2(a2, wf[64 + k],  hv[k]); dot2(a6, wf[80 + k],  hv[16 + k]);
                        dot2(a3, wf[96 + k],  hv[k]); dot2(a7, wf[112 + k], hv[16 + k]);
                    }
                    float sx = rdlane_(xp.x, j), sy = rdlane_(xp.y, j);
                    float pi = a0 + a4 + b0[0] + wx[0] * sx + wy[0] * sy;
                    float pf = a1 + a5 + b0[1] + wx[1] * sx + wy[1] * sy;
                    float pg = a2 + a6 + b0[2] + wx[2] * sx + wy[2] * sy;
                    float po = a3 + a7 + b0[3] + wx[3] * sx + wy[3] * sy;
                    float ai = sigf_(pi), af = sigf_(pf), ag = tanhf2_(pg), ao = sigf_(po);
                    c0 = fmaf(af, c0, ai * ag);
                    float h0n = ao * tanhf2_(c0);
                    h0r[u & 63][lane] = (_Float16)h0n;
                    // per-wave DS in-order: readback sees the write (R13 ✓)
                    const int4* rp = (const int4*)&h0r[u & 63][0];
                    int4 r0 = rp[0], r1 = rp[1], r2 = rp[2], r3 = rp[3];
                    int4 r4 = rp[4], r5 = rp[5], r6 = rp[6], r7 = rp[7];
                    UNP4(hv, 0, r0);  UNP4(hv, 4, r1);  UNP4(hv, 8, r2);  UNP4(hv, 12, r3);
                    UNP4(hv, 16, r4); UNP4(hv, 20, r5); UNP4(hv, 24, r6); UNP4(hv, 28, r7);
                }
            }
            __syncthreads();
        }
    } else if (w == 1) {
        // ================= wave 1 (SIMD1): L1 input-to-hidden =================
        h2 wf[128];
        #pragma unroll
        for (int g = 0; g < 4; ++g) {
            const float* r = Wih1 + ((g << 6) + lane) * 64;
            #pragma unroll
            for (int k = 0; k < 32; ++k) wf[g * 32 + k] = F2H2(r[2 * k], r[2 * k + 1]);
        }
        __syncthreads();
        for (int I = 0; I < NI; ++I) {
            const int tb = (I << 4) - 16;
            if (tb >= 0 && tb < Tn) {
                #pragma unroll 1
                for (int j = 0; j < 16; ++j) {
                    const int t = tb + j;
                    const int4* rp = (const int4*)&h0r[t & 63][0];
                    int4 r0 = rp[0], r1 = rp[1], r2 = rp[2], r3 = rp[3];
                    int4 r4 = rp[4], r5 = rp[5], r6 = rp[6], r7 = rp[7];
                    h2 hv[32];
                    UNP4(hv, 0, r0);  UNP4(hv, 4, r1);  UNP4(hv, 8, r2);  UNP4(hv, 12, r3);
                    UNP4(hv, 16, r4); UNP4(hv, 20, r5); UNP4(hv, 24, r6); UNP4(hv, 28, r7);
                    float a0 = 0, a1 = 0, a2 = 0, a3 = 0, a4 = 0, a5 = 0, a6 = 0, a7 = 0;
                    #pragma unroll
                    for (int k = 0; k < 16; ++k) {
                        dot2(a0, wf[k],       hv[k]); dot2(a4, wf[16 + k],  hv[16 + k]);
                        dot2(a1, wf[32 + k],  hv[k]); dot2(a5, wf[48 + k],  hv[16 + k]);
                        dot2(a2, wf[64 + k],  hv[k]); dot2(a6, wf[80 + k],  hv[16 + k]);
                        dot2(a3, wf[96 + k],  hv[k]); dot2(a7, wf[112 + k], hv[16 + k]);
                    }
                    g1r[t & 31][lane] = make_float4(a0 + a4, a1 + a5, a2 + a6, a3 + a7);
                }
            }
            __syncthreads();
        }
    } else if (w == 2) {
        // ================= wave 2 (SIMD2): L1 hidden + combine =================
        h2 wf[128]; float b1[4];
        #pragma unroll
        for (int g = 0; g < 4; ++g) {
            const int row = (g << 6) + lane;
            const float* r = Whh1 + row * 64;
            #pragma unroll
            for (int k = 0; k < 32; ++k) wf[g * 32 + k] = F2H2(r[2 * k], r[2 * k + 1]);
            b1[g] = bih1[row] + bhh1[row];
        }
        h2 hv[32];
        #pragma unroll
        for (int k = 0; k < 32; ++k) hv[k] = F2H2(0.f, 0.f);
        float c1 = 0.f;
        __syncthreads();
        for (int I = 0; I < NI; ++I) {
            const int tb = (I << 4) - 32;
            if (tb >= 0 && tb < Tn) {
                float4 pcur = g1r[tb & 31][lane];
                #pragma unroll 1
                for (int j = 0; j < 16; ++j) {
                    const int t = tb + j;
                    float4 pnext = pcur;
                    if (j < 15) pnext = g1r[(t + 1) & 31][lane];
                    float a0 = 0, a1 = 0, a2 = 0, a3 = 0, a4 = 0, a5 = 0, a6 = 0, a7 = 0;
                    #pragma unroll
                    for (int k = 0; k < 16; ++k) {
                        dot2(a0, wf[k],       hv[k]); dot2(a4, wf[16 + k],  hv[16 + k]);
                        dot2(a1, wf[32 + k],  hv[k]); dot2(a5, wf[48 + k],  hv[16 + k]);
                        dot2(a2, wf[64 + k],  hv[k]); dot2(a6, wf[80 + k],  hv[16 + k]);
                        dot2(a3, wf[96 + k],  hv[k]); dot2(a7, wf[112 + k], hv[16 + k]);
                    }
                    float pi = pcur.x + a0 + a4 + b1[0];
                    float pf = pcur.y + a1 + a5 + b1[1];
                    float pg = pcur.z + a2 + a6 + b1[2];
                    float po = pcur.w + a3 + a7 + b1[3];
                    float ai = sigf_(pi), af = sigf_(pf), ag = tanhf2_(pg), ao = sigf_(po);
                    c1 = fmaf(af, c1, ai * ag);
                    float h1n = ao * tanhf2_(c1);
                    h1r[t & 63][lane] = (_Float16)h1n;
                    const int4* rp = (const int4*)&h1r[t & 63][0];
                    int4 r0 = rp[0], r1 = rp[1], r2 = rp[2], r3 = rp[3];
                    int4 r4 = rp[4], r5 = rp[5], r6 = rp[6], r7 = rp[7];
                    UNP4(hv, 0, r0);  UNP4(hv, 4, r1);  UNP4(hv, 8, r2);  UNP4(hv, 12, r3);
                    UNP4(hv, 16, r4); UNP4(hv, 20, r5); UNP4(hv, 24, r6); UNP4(hv, 28, r7);
                    pcur = pnext;
                }
            }
            __syncthreads();
        }
    } else if (w == 4) {
        // ========= wave 4 (SIMD0, light): physics + health scan =========
        if (lane == 0) {
            float p1[32];
            for (int o = 0; o < 32; ++o) {
                float a = pbb1[o];
                for (int k = 0; k < 3; ++k) a += pbW1[o * 3 + k] * sf[b * 3 + k];
                p1[o] = fmaxf(a, 0.f);
            }
            float p2[16];
            for (int o = 0; o < 16; ++o) {
                float a = pbb2[o];
                for (int k = 0; k < 32; ++k) a += pbW2[o * 32 + k] * p1[k];
                p2[o] = fmaxf(a, 0.f);
            }
            float Ea = pbb3[0], lA = pbb3[1];
            for (int k = 0; k < 16; ++k) { Ea += pbW3[k] * p2[k]; lA += pbW3[16 + k] * p2[k]; }
            phys_s[0] = __expf(lA);
            phys_s[1] = -Ea * 1000.0f / 8.314f;
            phys_s[2] = Ea;
            phys_s[3] = lA;
        }
        float hst = 1.0f;
        __syncthreads();
        for (int I = 0; I < NI; ++I) {
            const int t0s = (I << 4) - 80;
            if (t0s >= 0 && t0s < Tn) {
                const int t = lane;
                const float Af = phys_s[0], ne = phys_s[1];
                float a_ = 0.f, l_ = -1e30f, u_ = 1e30f;
                if (t < 16) {
                    float dg = degb[(t0s + t) & 31];
                    float tK = tsb[2 * (t0s + t)] + 273.15f;
                    float arr = Af * __expf(ne * rcpf_(tK));
                    a_ = -(0.7f * dg + 0.3f * arr);
                    l_ = 0.f; u_ = 1.f;
                }
                #pragma unroll
                for (int d = 1; d < 16; d <<= 1) {
                    float pa = __shfl_up(a_, d);
                    float pl = __shfl_up(l_, d);
                    float pu = __shfl_up(u_, d);
                    if (t >= d && t < 16) {
                        float na = pa + a_;
                        float nl = fminf(fmaxf(pl + a_, l_), u_);
                        float nu = fminf(fmaxf(pu + a_, l_), u_);
                        a_ = na; l_ = nl; u_ = nu;
                    }
                }
                float hval = fminf(fmaxf(hst + a_, l_), u_);
                if (t < 16) { hltb[(t0s + t) & 31] = hval; outH[t0s + t] = hval; }
                hst = __shfl(hval, 15);
            }
            __syncthreads();
        }
    } else {
        // ==== waves 3,5,6,7 (SIMD 3,1,2,3): epilogue stages A/B/D ====
        const int ew = (w == 3) ? 0 : (w - 4);        // 0..3
        const int jj = lane & 31, hh = lane >> 5;
        h2 w1h[16], w2h[8], wd1h[16], wd2h[16], wr1h[8];
        float wt0, wt1, wt2, bb1, seb1r, seb2r, bb2, w3r, whc, brD, w2rD, drb3r, rub2r;
        {
            const float* r = seW1 + jj * 64 + hh * 32;
            #pragma unroll
            for (int k = 0; k < 16; ++k) w1h[k] = F2H2(r[2 * k], r[2 * k + 1]);
            r = seW2 + jj * 32 + hh * 16;
            #pragma unroll
            for (int k = 0; k < 8; ++k) w2h[k] = F2H2(r[2 * k], r[2 * k + 1]);
            r = drW1 + lane * 35;
            #pragma unroll
            for (int k = 0; k < 16; ++k) wd1h[k] = F2H2(r[2 * k], r[2 * k + 1]);
            wt0 = r[32]; wt1 = r[33]; wt2 = r[34];
            r = drW2 + jj * 64 + hh * 32;
            #pragma unroll
            for (int k = 0; k < 16; ++k) wd2h[k] = F2H2(r[2 * k], r[2 * k + 1]);
            r = ruW1 + jj * 33 + hh * 16;
            #pragma unroll
            for (int k = 0; k < 8; ++k) wr1h[k] = F2H2(r[2 * k], r[2 * k + 1]);
            seb1r = seb1[jj]; seb2r = seb2[jj];
            bb1 = drb1[lane]; bb2 = drb2[jj]; w3r = drW3[jj];
            whc = ruW1[jj * 33 + 32]; brD = rub1[jj]; w2rD = ruW2[jj];
            drb3r = drb3[0]; rub2r = rub2[0];
        }
        __syncthreads();
        for (int I = 0; I < NI; ++I) {
            const int Abase = (I << 4) - 48;
            const int Bbase = (I << 4) - 64;
            const int Dbase = (I << 4) - 96;
            float tpre[4];
            if (Bbase >= 0 && Bbase < Tn) {
                #pragma unroll
                for (int i = 0; i < 4; ++i) tpre[i] = tsb[2 * (Bbase + (ew << 2) + i)];
            }
            // ---- stage A: se1 + se2 ----
            if (Abase >= 0 && Abase < Tn) {
                #pragma unroll 1
                for (int i = 0; i < 4; ++i) {
                    const int pos = Abase + (ew << 2) + i;
                    const int slot = pos & 63;
                    const int4* hp = (const int4*)(&h1r[slot][hh * 32]);
                    int4 q0 = hp[0], q1 = hp[1], q2 = hp[2], q3 = hp[3];
                    h2 hv16[16];
                    UNP4(hv16, 0, q0); UNP4(hv16, 4, q1); UNP4(hv16, 8, q2); UNP4(hv16, 12, q3);
                    float acc = 0.f;
                    #pragma unroll
                    for (int k = 0; k < 16; ++k) dot2(acc, w1h[k], hv16[k]);
                    acc += __shfl_xor(acc, 32);
                    float se1v = fmaxf(acc + seb1r, 0.f);
                    if (hh == 0) se1b[ew][jj] = (_Float16)se1v;
                    LGKM0();
                    const int4* sp = (const int4*)(&se1b[ew][hh * 16]);
                    int4 s0 = sp[0], s1 = sp[1];
                    h2 sv[8];
                    UNP4(sv, 0, s0); UNP4(sv, 4, s1);
                    float a2 = 0.f;
                    #pragma unroll
                    for (int k = 0; k < 8; ++k) dot2(a2, w2h[k], sv[k]);
                    a2 += __shfl_xor(a2, 32);
                    if (hh == 0) ssb[slot][jj] = (_Float16)(a2 + seb2r);
                }
            }
            // ---- stage B: dr1 + dr2 + dr3 ----
            if (Bbase >= 0 && Bbase < Tn) {
                const float ea_ = phys_s[2], la_ = phys_s[3];
                #pragma unroll 1
                for (int i = 0; i < 4; ++i) {
                    const int pos = Bbase + (ew << 2) + i;
                    const int slot = pos & 63;
                    const int4* xp = (const int4*)(&ssb[slot][0]);
                    int4 x0 = xp[0], x1 = xp[1], x2 = xp[2], x3 = xp[3];
                    h2 xv[16];
                    UNP4(xv, 0, x0); UNP4(xv, 4, x1); UNP4(xv, 8, x2); UNP4(xv, 12, x3);
                    float acc = 0.f;
                    #pragma unroll
                    for (int k = 0; k < 16; ++k) dot2(acc, wd1h[k], xv[k]);
                    acc += wt0 * tpre[i] + wt1 * ea_ + wt2 * la_;
                    dr1b[ew][lane] = (_Float16)fmaxf(acc + bb1, 0.f);
                    LGKM0();
                    const int4* dp = (const int4*)(&dr1b[ew][hh * 32]);
                    int4 d0 = dp[0], d1 = dp[1], d2 = dp[2], d3 = dp[3];
                    h2 dv[16];
                    UNP4(dv, 0, d0); UNP4(dv, 4, d1); UNP4(dv, 8, d2); UNP4(dv, 12, d3);
                    float a2 = 0.f;
                    #pragma unroll
                    for (int k = 0; k < 16; ++k) dot2(a2, wd2h[k], dv[k]);
                    a2 += __shfl_xor(a2, 32);
                    float tt = w3r * fmaxf(a2 + bb2, 0.f);
                    float sum = wsum64_dpp_(tt);       // valid in lane 63; jj counted 2x
                    float tot = rdlane_(sum, 63);
                    float deg = 0.5f * tot + drb3r;
                    if (lane == 0) { degb[pos & 31] = deg; outD[pos] = deg; }
                }
            }
            // ---- stage D: rul head ----
            if (Dbase >= 0 && Dbase < Tn) {
                #pragma unroll 1
                for (int i = 0; i < 4; ++i) {
                    const int pos = Dbase + (ew << 2) + i;
                    const int slot = pos & 63;
                    const int4* xp = (const int4*)(&ssb[slot][hh * 16]);
                    int4 x0 = xp[0], x1 = xp[1];
                    h2 xv[8];
                    UNP4(xv, 0, x0); UNP4(xv, 4, x1);
                    float acc = 0.f;
                    #pragma unroll
                    for (int k = 0; k < 8; ++k) dot2(acc, wr1h[k], xv[k]);
                    acc += __shfl_xor(acc, 32);
                    float a = acc + brD + whc * hltb[pos & 31];
                    float pp = w2rD * fmaxf(a, 0.f);
                    float sum = wsum64_dpp_(pp);
                    float tot = rdlane_(sum, 63);
                    if (lane == 0) outR[pos] = fmaxf(0.5f * tot + rub2r, 0.f);
                }
            }
            __syncthreads();
        }
    }
}

extern "C" void kernel_launch(void* const* d_in, const int* in_sizes, int n_in,
                              void* d_out, int out_size, void* d_ws, size_t ws_size,
                              hipStream_t stream) {
    const float* ts   = (const float*)d_in[0];
    const float* sf   = (const float*)d_in[1];
    const float* Wih0 = (const float*)d_in[2];
    const float* Whh0 = (const float*)d_in[3];
    const float* bih0 = (const float*)d_in[4];
    const float* bhh0 = (const float*)d_in[5];
    const float* Wih1 = (const float*)d_in[6];
    const float* Whh1 = (const float*)d_in[7];
    const float* bih1 = (const float*)d_in[8];
    const float* bhh1 = (const float*)d_in[9];
    const float* seW1 = (const float*)d_in[10];
    const float* seb1 = (const float*)d_in[11];
    const float* seW2 = (const float*)d_in[12];
    const float* seb2 = (const float*)d_in[13];
    const float* pbW1 = (const float*)d_in[14];
    const float* pbb1 = (const float*)d_in[15];
    const float* pbW2 = (const float*)d_in[16];
    const float* pbb2 = (const float*)d_in[17];
    const float* pbW3 = (const float*)d_in[18];
    const float* pbb3 = (const float*)d_in[19];
    const float* drW1 = (const float*)d_in[20];
    const float* drb1 = (const float*)d_in[21];
    const float* drW2 = (const float*)d_in[22];
    const float* drb2 = (const float*)d_in[23];
    const float* drW3 = (const float*)d_in[24];
    const float* drb3 = (const float*)d_in[25];
    const float* ruW1 = (const float*)d_in[26];
    const float* rub1 = (const float*)d_in[27];
    const float* ruW2 = (const float*)d_in[28];
    const float* rub2 = (const float*)d_in[29];
    float* out = (float*)d_out;

    fused_rul_kernel<<<dim3(Bn), dim3(NT), 0, stream>>>(
        ts, sf, Wih0, Whh0, bih0, bhh0, Wih1, Whh1, bih1, bhh1,
        seW1, seb1, seW2, seb2, pbW1, pbb1, pbW2, pbb2, pbW3, pbb3,
        drW1, drb1, drW2, drb2, drW3, drb3, ruW1, rub1, ruW2, rub2, out);
}